// Round 9
// baseline (353.590 us; speedup 1.0000x reference)
//
#include <hip/hip_runtime.h>

#define H    64
#define F    256
#define NSEG 256
#define SCB  2048   // scan elements per block
#define MB   64     // qkv node rows per block

typedef float          f32x4v __attribute__((ext_vector_type(4)));
typedef short          bf16x8 __attribute__((ext_vector_type(8)));

// ---------------------------------------------------------------------------
// Kernel 0: transpose+split W (3 x [256,64] fp32) into Wt[mat*64+j][k] bf16
// hi/lo (truncation split: w = hi + lo + O(2^-17)).  192 blocks = (mat,j).
// ---------------------------------------------------------------------------
__global__ __launch_bounds__(256) void w_convert(
    const float* __restrict__ Wq, const float* __restrict__ Wk,
    const float* __restrict__ Wv,
    unsigned short* __restrict__ wt_hi, unsigned short* __restrict__ wt_lo)
{
    const int b   = blockIdx.x;        // mat*64 + j
    const int mat = b >> 6;
    const int j   = b & 63;
    const int t   = threadIdx.x;       // k
    const float* W = (mat == 0) ? Wq : (mat == 1) ? Wk : Wv;
    float f = W[t * H + j];
    unsigned u = __float_as_uint(f);
    unsigned short hi = (unsigned short)(u >> 16);
    float rf = f - __uint_as_float(u & 0xFFFF0000u);
    unsigned short lo = (unsigned short)(__float_as_uint(rf) >> 16);
    const size_t o = (size_t)b * F + t;
    wt_hi[o] = hi;
    wt_lo[o] = lo;
}

// ---------------------------------------------------------------------------
// Kernel 1: QKV via split-bf16 MFMA -- LDS-free, barrier-free.
// r8 post-mortem: 8 full-drain barriers + ~2 blocks/CU = latency-dead
// (MfmaUtil 6%).  The MFMA A-layout (A[m=l15][k=quad*8..7]) maps directly to
// per-lane 32B global loads of x rows; the 16KB/chunk tile is L1-hot across
// the block's 4 waves.  fp32->bf16 hi/lo split done in registers.  With no
// barriers the compiler pipelines chunk k+1 loads under chunk k MFMAs.
//   acc += xh*wh + xh*wl + xl*wh    (xl*wl ~ 2^-17 dropped)
// Wave = output-column tile nt; 4 m-tiles x 3 mats accumulated (12 f32x4).
// Fused in-degree histogram rides along (fire-and-forget atomics).
// ---------------------------------------------------------------------------
__global__ __launch_bounds__(256, 4) void qkv_mfma_hist(
    const float* __restrict__ x,
    const unsigned short* __restrict__ wt_hi,
    const unsigned short* __restrict__ wt_lo,
    const float* __restrict__ bq, const float* __restrict__ bk,
    const float* __restrict__ bv,
    float* __restrict__ q, float* __restrict__ k, float* __restrict__ v,
    const int* __restrict__ ei, int* __restrict__ counts,
    int N, int E)
{
    const int t = threadIdx.x;

    // --- fused histogram (independent; no result needed) ---
    {
        int e = blockIdx.x * 1024 + t;
        #pragma unroll
        for (int u = 0; u < 4; ++u) {
            if (e < E) {
                int dst = ei[E + e];
                dst = min(max(dst, 0), N - 1);
                atomicAdd(&counts[dst], 1);
            }
            e += 256;
        }
    }

    const int block0 = blockIdx.x * MB;
    const int lane = t & 63;
    const int nt   = t >> 6;       // wave id = output col tile
    const int l15  = lane & 15;
    const int quad = lane >> 4;

    f32x4v acc[12];                // [mat*4 + mtile]
    #pragma unroll
    for (int i = 0; i < 12; ++i) acc[i] = (f32x4v)0.f;

    // clamped row index per m-tile (OOB rows masked at epilogue)
    int arow[4];
    #pragma unroll
    for (int mt = 0; mt < 4; ++mt)
        arow[mt] = min(block0 + mt * 16 + l15, N - 1);

    const size_t wbase = (size_t)(nt * 16 + l15) * F + quad * 8;

    #pragma unroll
    for (int kb = 0; kb < F; kb += 64) {
        #pragma unroll
        for (int sk = 0; sk < 2; ++sk) {
            const int k0 = kb + sk * 32 + quad * 8;

            // B frags for this (kb,sk): 3 mats x hi/lo (L1/L2-hot, 196KB)
            bf16x8 Bh[3], Bl[3];
            #pragma unroll
            for (int mat = 0; mat < 3; ++mat) {
                const size_t wo = wbase + (size_t)mat * 64 * F + kb + sk * 32;
                Bh[mat] = *(const bf16x8*)(wt_hi + wo);
                Bl[mat] = *(const bf16x8*)(wt_lo + wo);
            }

            #pragma unroll
            for (int mt = 0; mt < 4; ++mt) {
                // A frag: 8 consecutive fp32 from x row (2x dwordx4)
                const float* ap = x + (size_t)arow[mt] * F + k0;
                const float4 a0 = *(const float4*)ap;
                const float4 a1 = *(const float4*)(ap + 4);
                const float af[8] = {a0.x, a0.y, a0.z, a0.w,
                                     a1.x, a1.y, a1.z, a1.w};
                bf16x8 ah, al;
                #pragma unroll
                for (int i = 0; i < 8; ++i) {
                    unsigned ub = __float_as_uint(af[i]);
                    ah[i] = (short)(ub >> 16);
                    float rf = af[i] - __uint_as_float(ub & 0xFFFF0000u);
                    al[i] = (short)(__float_as_uint(rf) >> 16);
                }
                #pragma unroll
                for (int mat = 0; mat < 3; ++mat) {
                    f32x4v a = acc[mat * 4 + mt];
                    a = __builtin_amdgcn_mfma_f32_16x16x32_bf16(ah, Bh[mat], a, 0, 0, 0);
                    a = __builtin_amdgcn_mfma_f32_16x16x32_bf16(ah, Bl[mat], a, 0, 0, 0);
                    a = __builtin_amdgcn_mfma_f32_16x16x32_bf16(al, Bh[mat], a, 0, 0, 0);
                    acc[mat * 4 + mt] = a;
                }
            }
        }
    }

    // epilogue: C layout col = lane&15, row = quad*4 + reg  (m89-verified)
    float* outs[3] = {q, k, v};
    const float* biases[3] = {bq, bk, bv};
    const int col = nt * 16 + l15;
    #pragma unroll
    for (int mat = 0; mat < 3; ++mat) {
        float* dst = outs[mat];
        const float bb = biases[mat][col];
        #pragma unroll
        for (int mt = 0; mt < 4; ++mt) {
            #pragma unroll
            for (int r = 0; r < 4; ++r) {
                const int node = block0 + mt * 16 + quad * 4 + r;
                if (node < N)
                    dst[(size_t)node * H + col] = acc[mat * 4 + mt][r] + bb;
            }
        }
    }
}

// ---------------------------------------------------------------------------
// Scan phase A/B/C: exclusive scan of padded (x4) per-node counts.
// ---------------------------------------------------------------------------
__global__ __launch_bounds__(256) void scanA(
    const int* __restrict__ counts, int* __restrict__ offsets,
    int* __restrict__ bsum, int n)
{
    __shared__ int ps[256];
    const int t = threadIdx.x;
    const int i0 = blockIdx.x * SCB + t * 8;
    int loc[8];
    int s = 0;
    #pragma unroll
    for (int u = 0; u < 8; ++u) {
        int i = i0 + u;
        int c = (i < n) ? ((counts[i] + 3) & ~3) : 0;
        loc[u] = s; s += c;
    }
    ps[t] = s;
    __syncthreads();
    for (int off = 1; off < 256; off <<= 1) {
        int a = (t >= off) ? ps[t - off] : 0;
        __syncthreads();
        ps[t] += a;
        __syncthreads();
    }
    const int base = ps[t] - s;
    #pragma unroll
    for (int u = 0; u < 8; ++u) {
        int i = i0 + u;
        if (i < n) offsets[i] = base + loc[u];
    }
    if (t == 255) bsum[blockIdx.x] = ps[255];
}

__global__ void scanB(int* __restrict__ bsum, int nb)
{
    if (threadIdx.x == 0 && blockIdx.x == 0) {
        int run = 0;
        for (int i = 0; i < nb; ++i) { int v = bsum[i]; bsum[i] = run; run += v; }
    }
}

__global__ __launch_bounds__(256) void scanC(
    const int* __restrict__ bsum, int* __restrict__ offsets,
    int* __restrict__ cursor, int n)
{
    const int i0 = blockIdx.x * SCB + threadIdx.x * 8;
    const int add = bsum[blockIdx.x];
    #pragma unroll
    for (int u = 0; u < 8; ++u) {
        int i = i0 + u;
        if (i < n) { int o = offsets[i] + add; offsets[i] = o; cursor[i] = o; }
    }
}

// ---------------------------------------------------------------------------
// Reorder edges into dst-node order.  pack = src(16b) | seg(8b)<<16.
// ---------------------------------------------------------------------------
__global__ __launch_bounds__(256) void reorder_kernel(
    const int* __restrict__ ei, const int* __restrict__ batch,
    int* __restrict__ cursor, unsigned* __restrict__ epack, int E, int N)
{
    int e = blockIdx.x * 256 + threadIdx.x;
    if (e >= E) return;
    int src = ei[e];
    int dst = ei[E + e];
    src = min(max(src, 0), N - 1);
    dst = min(max(dst, 0), N - 1);
    int seg = batch[src];
    seg = min(max(seg, 0), NSEG - 1);
    int pos = atomicAdd(&cursor[dst], 1);
    epack[pos] = (unsigned)src | ((unsigned)seg << 16);
}

// ---------------------------------------------------------------------------
// Score: persistent grid, one wave per dst node; q[dst] in registers across
// its edges; 4 edges in flight (16-lane groups, float4 k gathers, 4-step
// shuffle reduce).  Per-block LDS denom histogram flushed once.
// ---------------------------------------------------------------------------
__global__ __launch_bounds__(256) void score_kernel(
    const float* __restrict__ q, const float* __restrict__ k,
    const unsigned* __restrict__ epack,
    const int* __restrict__ offsets, const int* __restrict__ counts,
    float* __restrict__ exps, float* __restrict__ denom, int N)
{
    __shared__ float sden[NSEG];
    const int t = threadIdx.x;
    sden[t] = 0.f;
    __syncthreads();

    const int lane16 = t & 15;
    const int grp    = (t >> 4) & 3;
    const int wave   = t >> 6;
    const int nwaves = gridDim.x * 4;

    const float4* q4 = (const float4*)q;
    const float4* k4 = (const float4*)k;

    for (int n = blockIdx.x * 4 + wave; n < N; n += nwaves) {
        const int off = offsets[n];
        const int cnt = counts[n];
        if (cnt == 0) continue;
        const float4 qv = q4[(size_t)n * 16 + lane16];
        for (int i = grp; i < cnt; i += 4) {
            const int pos = off + i;
            const unsigned p = epack[pos];
            const int src = p & 0xFFFF;
            const float4 kv = k4[(size_t)src * 16 + lane16];
            float d = kv.x * qv.x + kv.y * qv.y + kv.z * qv.z + kv.w * qv.w;
            d += __shfl_xor(d, 1, 64);
            d += __shfl_xor(d, 2, 64);
            d += __shfl_xor(d, 4, 64);
            d += __shfl_xor(d, 8, 64);
            if (lane16 == 0) {
                float ex = __expf(d * 0.125f);
                exps[pos] = ex;
                atomicAdd(&sden[(p >> 16) & 255], ex);
            }
        }
    }
    __syncthreads();
    float ds = sden[t];
    if (ds != 0.f) atomicAdd(&denom[t], ds);
}

// ---------------------------------------------------------------------------
// Accumulate: one wave per dst node, lane = feature, register accumulator,
// zero atomics.  LDS reciprocal table; 8-wide unrolled edge loop.
// ---------------------------------------------------------------------------
__global__ __launch_bounds__(256) void accum_kernel(
    const float* __restrict__ v, const float* __restrict__ exps,
    const unsigned* __restrict__ epack,
    const int* __restrict__ offsets, const int* __restrict__ counts,
    const float* __restrict__ denom, float* __restrict__ out, int N)
{
    __shared__ float rden[NSEG];
    const int t = threadIdx.x;
    rden[t] = 1.0f / (denom[t] + 1e-6f);
    __syncthreads();

    const int lane = t & 63;
    const int wave = t >> 6;
    const int n = blockIdx.x * 4 + wave;
    if (n >= N) return;

    const int off = offsets[n];
    const int cnt = counts[n];

    float acc = 0.f;
    int i = 0;
    for (; i + 8 <= cnt; i += 8) {
        const uint4  pa = *(const uint4*)(epack + off + i);
        const uint4  pb = *(const uint4*)(epack + off + i + 4);
        const float4 ea = *(const float4*)(exps + off + i);
        const float4 eb = *(const float4*)(exps + off + i + 4);
        const float v0 = v[(size_t)(pa.x & 0xFFFF) * H + lane];
        const float v1 = v[(size_t)(pa.y & 0xFFFF) * H + lane];
        const float v2 = v[(size_t)(pa.z & 0xFFFF) * H + lane];
        const float v3 = v[(size_t)(pa.w & 0xFFFF) * H + lane];
        const float v4_ = v[(size_t)(pb.x & 0xFFFF) * H + lane];
        const float v5 = v[(size_t)(pb.y & 0xFFFF) * H + lane];
        const float v6 = v[(size_t)(pb.z & 0xFFFF) * H + lane];
        const float v7 = v[(size_t)(pb.w & 0xFFFF) * H + lane];
        acc = fmaf(v0, ea.x * rden[(pa.x >> 16) & 255], acc);
        acc = fmaf(v1, ea.y * rden[(pa.y >> 16) & 255], acc);
        acc = fmaf(v2, ea.z * rden[(pa.z >> 16) & 255], acc);
        acc = fmaf(v3, ea.w * rden[(pa.w >> 16) & 255], acc);
        acc = fmaf(v4_, eb.x * rden[(pb.x >> 16) & 255], acc);
        acc = fmaf(v5, eb.y * rden[(pb.y >> 16) & 255], acc);
        acc = fmaf(v6, eb.z * rden[(pb.z >> 16) & 255], acc);
        acc = fmaf(v7, eb.w * rden[(pb.w >> 16) & 255], acc);
    }
    for (; i + 4 <= cnt; i += 4) {
        const uint4  pp = *(const uint4*)(epack + off + i);
        const float4 ee = *(const float4*)(exps + off + i);
        const float v0 = v[(size_t)(pp.x & 0xFFFF) * H + lane];
        const float v1 = v[(size_t)(pp.y & 0xFFFF) * H + lane];
        const float v2 = v[(size_t)(pp.z & 0xFFFF) * H + lane];
        const float v3 = v[(size_t)(pp.w & 0xFFFF) * H + lane];
        acc = fmaf(v0, ee.x * rden[(pp.x >> 16) & 255], acc);
        acc = fmaf(v1, ee.y * rden[(pp.y >> 16) & 255], acc);
        acc = fmaf(v2, ee.z * rden[(pp.z >> 16) & 255], acc);
        acc = fmaf(v3, ee.w * rden[(pp.w >> 16) & 255], acc);
    }
    for (; i < cnt; ++i) {
        const unsigned p = epack[off + i];
        acc = fmaf(v[(size_t)(p & 0xFFFF) * H + lane],
                   exps[off + i] * rden[(p >> 16) & 255], acc);
    }
    out[(size_t)n * H + lane] = acc;
}

extern "C" void kernel_launch(void* const* d_in, const int* in_sizes, int n_in,
                              void* d_out, int out_size, void* d_ws, size_t ws_size,
                              hipStream_t stream)
{
    const float* x   = (const float*)d_in[0];
    const float* Wq  = (const float*)d_in[1];
    const float* bq  = (const float*)d_in[2];
    const float* Wk  = (const float*)d_in[3];
    const float* bk  = (const float*)d_in[4];
    const float* Wv  = (const float*)d_in[5];
    const float* bv  = (const float*)d_in[6];
    const int* ei    = (const int*)d_in[7];
    const int* batch = (const int*)d_in[8];

    const int N = in_sizes[8];        // 50000
    const int E = in_sizes[7] / 2;    // 800000
    const int EP = E + 3 * N + 16;    // padded edge-slot capacity

    float*    q       = (float*)d_ws;
    float*    k       = q + (size_t)N * H;
    float*    v       = k + (size_t)N * H;
    float*    exps    = v + (size_t)N * H;
    unsigned* epack   = (unsigned*)(exps + EP);
    int*      counts  = (int*)(epack + EP);
    int*      offsets = counts + N;
    int*      cursor  = offsets + N;
    int*      bsum    = cursor + N;
    float*    denom   = (float*)(bsum + 64);
    unsigned short* wt_hi = (unsigned short*)(denom + NSEG);
    unsigned short* wt_lo = wt_hi + 3 * H * F;

    hipMemsetAsync(counts, 0, N * sizeof(int), stream);
    hipMemsetAsync(denom, 0, NSEG * sizeof(float), stream);

    const int QB = (N + MB - 1) / MB;       // 782 (covers E/1024 hist chunks)
    const int NBSC = (N + SCB - 1) / SCB;   // 25 scan blocks

    w_convert<<<3 * H, 256, 0, stream>>>(Wq, Wk, Wv, wt_hi, wt_lo);

    qkv_mfma_hist<<<QB, 256, 0, stream>>>(
        x, wt_hi, wt_lo, bq, bk, bv, q, k, v, ei, counts, N, E);

    scanA<<<NBSC, 256, 0, stream>>>(counts, offsets, bsum, N);
    scanB<<<1, 64, 0, stream>>>(bsum, NBSC);
    scanC<<<NBSC, 256, 0, stream>>>(bsum, offsets, cursor, N);

    reorder_kernel<<<(E + 255) / 256, 256, 0, stream>>>(
        ei, batch, cursor, epack, E, N);

    score_kernel<<<2048, 256, 0, stream>>>(
        q, k, epack, offsets, counts, exps, denom, N);

    accum_kernel<<<(N + 3) / 4, 256, 0, stream>>>(
        v, exps, epack, offsets, counts, denom, (float*)d_out, N);
}